// Round 7
// baseline (410.156 us; speedup 1.0000x reference)
//
#include <hip/hip_runtime.h>
#include <hip/hip_bf16.h>
#include <cstdint>

typedef __attribute__((ext_vector_type(8))) short short8;
typedef __attribute__((ext_vector_type(4))) float f32x4;
typedef unsigned short ushort_t;

#define MM 8192
#define NN 4096
#define KK 4096

#define BM 128
#define BN 128
#define BK 64
#define NT (KK / BK)  // 64 K-tiles

#define MFMA_BF16 __builtin_amdgcn_mfma_f32_16x16x32_bf16

// fp32 -> bf16 round-to-nearest-even (inputs are finite)
__device__ __forceinline__ ushort_t f2bf(float f) {
  uint32_t u = __builtin_bit_cast(uint32_t, f);
  u = (u + 0x7FFFu + ((u >> 16) & 1u)) >> 16;
  return (ushort_t)u;
}

// fused activation chain: leaky_relu -> +y -> mish -> hardswish + 0.5
__device__ __forceinline__ float epilogue(float v, float yv) {
  v = fmaxf(v, 0.01f * v);  // leaky relu
  v += yv;
  const float vc = fminf(v, 15.f);
  const float t = __builtin_amdgcn_exp2f(vc * 1.44269504f);  // e^vc
  const float d = t * t + 2.f * t;
  const float mi = v * d * __builtin_amdgcn_rcpf(d + 2.f);   // mish
  const float r6 = fminf(fmaxf(mi + 3.f, 0.f), 6.f);
  return mi * r6 * (1.f / 6.f) + 0.5f;                       // hardswish + 0.5
}

// async 16B global->LDS (LDS dest is wave-uniform base + lane*16)
__device__ __forceinline__ void gload_lds16(const void* g, void* l) {
  __builtin_amdgcn_global_load_lds(
      (const __attribute__((address_space(1))) unsigned int*)g,
      (__attribute__((address_space(3))) unsigned int*)l, 16, 0, 0);
}

#define CVT_BLOCKS ((MM * KK) / (256 * 8))      // 16384
#define WT_BLOCKS ((NN / 32) * (KK / 32))       // 16384

// ---------------- merged prep: X convert (bid<CVT_BLOCKS) + W transpose ----------------
template <int DO_X>
__global__ void prep_kernel(const float* __restrict__ X, ushort_t* __restrict__ XB,
                            const float* __restrict__ W, ushort_t* __restrict__ WT) {
  __shared__ float t[32][33];
  const int bid = blockIdx.x;
  const int tid = threadIdx.x;
  if (DO_X && bid < CVT_BLOCKS) {
    const size_t i = ((size_t)bid * 256 + tid) * 8;
    f32x4 v0 = __builtin_nontemporal_load(reinterpret_cast<const f32x4*>(&X[i]));
    f32x4 v1 = __builtin_nontemporal_load(reinterpret_cast<const f32x4*>(&X[i + 4]));
    short8 o;
    o[0] = (short)f2bf(v0[0]); o[1] = (short)f2bf(v0[1]);
    o[2] = (short)f2bf(v0[2]); o[3] = (short)f2bf(v0[3]);
    o[4] = (short)f2bf(v1[0]); o[5] = (short)f2bf(v1[1]);
    o[6] = (short)f2bf(v1[2]); o[7] = (short)f2bf(v1[3]);
    *reinterpret_cast<short8*>(&XB[i]) = o;
  } else {
    const int b2 = DO_X ? (bid - CVT_BLOCKS) : bid;
    const int n0 = (b2 & 127) * 32, k0 = (b2 >> 7) * 32;
    const int tx = tid & 31, ty = tid >> 5;  // 32 x 8
#pragma unroll
    for (int i = ty; i < 32; i += 8)
      t[i][tx] = __builtin_nontemporal_load(&W[(size_t)(k0 + i) * NN + n0 + tx]);
    __syncthreads();
#pragma unroll
    for (int i = ty; i < 32; i += 8)
      WT[(size_t)(n0 + i) * KK + k0 + tx] = f2bf(t[tx][i]);
  }
}

// -------- main fused GEMM: R0 champion + dbuf + stage-first (drain hidden) --------
// R7. Resource model (R5/R6 counters + m134/m201 cross-check): the CU-shared
// LDS read pipe is the binding resource (~768 cyc/128^2-K-step vs 621 MFMA);
// overlap quality decides everything. R0's 4 desync blocks/CU overlapped well
// (48% MfmaUtil) but exposed the DMA drain each K-step (issue->sync-drain with
// nothing between). This kernel = R0 VERBATIM (tile/maps/swizzle/block-map/
// epilogue) except:
//   (a) LDS double-buffered (64 KB) -> 2 desync blocks/CU (m114 co-sched);
//   (b) loop = stage(nxt,k+1) FIRST, compute(cur), __syncthreads() -- the
//       barrier's compiler-emitted vmcnt drain lands after ~1400 cyc of
//       compute => ~free (the m97 drain-stall removed by construction);
//   (c) zero-VALU ds-read addressing: 4 base VGPRs, buffer/fragment selected
//       by compile-time offset: imm (buf*16384B + i*2048B <= 22.5KB);
//   (d) u32 stage offsets + uniform k1 add (8 v_add/K-step).
// Hazards: stage(nxt)@t overwrites data last read at t-1's compute, retired by
// t-1's syncthreads lgkm-drain -> safe. compute(cur)@t reads data staged @t-1,
// drained by t-1's syncthreads vmcnt-drain -> safe. Tail stage wraps to k=0
// (in-bounds, never read).
__global__ __launch_bounds__(256, 2) void gemm_bf16_d(
    const ushort_t* __restrict__ XB, const ushort_t* __restrict__ WT,
    const float* __restrict__ Y, float* __restrict__ O) {
  __shared__ ushort_t As[2 * BM * BK];  // 32 KB (2 bufs)
  __shared__ ushort_t Bs[2 * BN * BK];  // 32 KB

  // block map (R0 champion): xcd = wg&7 owns 4-wide n-band, m-fastest.
  // Per-XCD B working set = 4 panels = 4MB = L2-resident; A once via L3.
  const int wg = blockIdx.x;
  const int xcd = wg & 7;
  const int local = wg >> 3;           // 0..255
  const int bm0 = (local >> 2) * BM;   // 64 m-tiles, fastest
  const int bn0 = (xcd * 4 + (local & 3)) * BN;  // 4-wide n-band per XCD

  const int tid = threadIdx.x;
  const int lane = tid & 63;
  const int wid = tid >> 6;
  const int wm = (wid >> 1) * 64, wn = (wid & 1) * 64;
  const int lr = lane & 15, lg = lane >> 4, lr7 = lane & 7;

  // staging (R0 lane math): wave wid stages chunks j=0..3 (8 rows x 8 slots);
  // lane -> row wid*32 + j*8 + (lane>>3), dest slot lane&7 (linear),
  // src slot (lane&7)^(lane>>3) so LDS[row][s] = G[row][s^(row&7)]
  const int s_sub = lane >> 3;
  const int s_chunk = (lane & 7) ^ s_sub;
  uint32_t offA[4], offB[4];
#pragma unroll
  for (int j = 0; j < 4; ++j) {
    const int srow = wid * 32 + j * 8 + s_sub;
    offA[j] = (uint32_t)(bm0 + srow) * KK + s_chunk * 8;
    offB[j] = (uint32_t)(bn0 + srow) * KK + s_chunk * 8;
  }

  // fragment read bases (R0): row = wm/wn + i*16 + lr (row&7 == lr7);
  // slot(ks) = ((ks<<2)|lg) ^ lr7. Buffer + i handled via offset: imm.
  const int aRow = (wm + lr) * BK;
  const int bRow = (wn + lr) * BK;
  const int slot0 = ((lg ^ lr7) << 3);        // ks=0, elements
  const int slot1 = (((4 | lg) ^ lr7) << 3);  // ks=1
  const ushort_t* a0 = As + aRow + slot0;     // + buf*8192 + i*1024 (imm)
  const ushort_t* a1 = As + aRow + slot1;
  const ushort_t* b0 = Bs + bRow + slot0;
  const ushort_t* b1 = Bs + bRow + slot1;

  f32x4 acc[4][4] = {};

#define STAGE(buf, kv)                                                         \
  _Pragma("unroll") for (int j = 0; j < 4; ++j) {                              \
    gload_lds16(XB + offA[j] + (kv), As + (buf) * 8192 + (wid * 4 + j) * 512); \
    gload_lds16(WT + offB[j] + (kv), Bs + (buf) * 8192 + (wid * 4 + j) * 512); \
  }

#define COMPUTE(buf)                                                           \
  _Pragma("unroll") for (int ks = 0; ks < 2; ++ks) {                           \
    const ushort_t* ap = ks ? a1 : a0;                                         \
    const ushort_t* bp = ks ? b1 : b0;                                         \
    short8 a[4], b[4];                                                         \
    _Pragma("unroll") for (int i = 0; i < 4; ++i) {                            \
      a[i] = *reinterpret_cast<const short8*>(ap + (buf) * 8192 + i * 1024);   \
      b[i] = *reinterpret_cast<const short8*>(bp + (buf) * 8192 + i * 1024);   \
    }                                                                          \
    _Pragma("unroll") for (int i = 0; i < 4; ++i)                              \
        _Pragma("unroll") for (int j = 0; j < 4; ++j)                          \
            acc[i][j] = MFMA_BF16(a[i], b[j], acc[i][j], 0, 0, 0);             \
  }

#define KSTEP(cur, nxt, t)                                                     \
  {                                                                            \
    const int k1 = (((t) + 1) & (NT - 1)) * BK;                                \
    STAGE(nxt, k1);   /* issued first: lands under compute */                  \
    COMPUTE(cur);                                                              \
    __syncthreads();  /* drain (~0: DMA issued ~1400 cyc ago) + swap fence */  \
  }

  // ---- prologue: stage tile 0 into buf 0 ----
  STAGE(0, 0);
  __syncthreads();

#pragma unroll 1
  for (int t = 0; t < NT; t += 2) {
    KSTEP(0, 1, t);
    KSTEP(1, 0, t + 1);
  }

#undef STAGE
#undef COMPUTE
#undef KSTEP

  // epilogue: C/D layout col=lane&15, row=(lane>>4)*4+r  [m89-verified]
#pragma unroll
  for (int i = 0; i < 4; ++i) {
#pragma unroll
    for (int j = 0; j < 4; ++j) {
#pragma unroll
      for (int r = 0; r < 4; ++r) {
        const int grow = bm0 + wm + i * 16 + lg * 4 + r;
        const int gcol = bn0 + wn + j * 16 + lr;
        const size_t idx = (size_t)grow * NN + gcol;
        const float yv = __builtin_nontemporal_load(&Y[idx]);
        __builtin_nontemporal_store(epilogue(acc[i][j][r], yv), &O[idx]);
      }
    }
  }
}

// ---------------- mid-tier (validated R1): reg-staged conversion GEMM ----------------
#define LDP 72
__global__ __launch_bounds__(256, 3) void gemm_fused(
    const float* __restrict__ X, const ushort_t* __restrict__ WT,
    const float* __restrict__ Y, float* __restrict__ O) {
  __shared__ ushort_t Asm[BM * LDP];
  __shared__ ushort_t Bsm[BN * LDP];

  const int nwg = (MM / BM) * (NN / BN);
  int wg = blockIdx.x;
  wg = (wg % 8) * (nwg / 8) + wg / 8;
  const int NTC = NN / BN;
  const int bm0 = (wg / NTC) * BM;
  const int bn0 = (wg % NTC) * BN;

  const int tid = threadIdx.x;
  const int lane = tid & 63;
  const int wid = tid >> 6;
  const int wm = (wid >> 1) * 64, wn = (wid & 1) * 64;
  const int lr = lane & 15, lg = lane >> 4;

  f32x4 acc[4][4] = {};

  const int arow = tid >> 2;
  const int ac = (tid & 3) * 4;
  const int brow = tid >> 1;
  const int bc0 = (tid & 1) * 32;

  for (int kt = 0; kt < KK; kt += BK) {
    __syncthreads();
#pragma unroll
    for (int p = 0; p < 2; ++p) {
      const int row = arow + p * 64;
      const float* src = &X[(size_t)(bm0 + row) * KK + kt];
#pragma unroll
      for (int j = 0; j < 4; ++j) {
        f32x4 v = *reinterpret_cast<const f32x4*>(&src[ac + j * 16]);
        uint2 packed;
        packed.x = (uint32_t)f2bf(v[0]) | ((uint32_t)f2bf(v[1]) << 16);
        packed.y = (uint32_t)f2bf(v[2]) | ((uint32_t)f2bf(v[3]) << 16);
        *reinterpret_cast<uint2*>(&Asm[row * LDP + ac + j * 16]) = packed;
      }
    }
    {
      const ushort_t* src = &WT[(size_t)(bn0 + brow) * KK + kt + bc0];
#pragma unroll
      for (int j = 0; j < 4; ++j) {
        short8 u = *reinterpret_cast<const short8*>(&src[j * 8]);
        *reinterpret_cast<short8*>(&Bsm[brow * LDP + bc0 + j * 8]) = u;
      }
    }
    __syncthreads();

#pragma unroll
    for (int ks = 0; ks < 2; ++ks) {
      short8 a[4], b[4];
#pragma unroll
      for (int i = 0; i < 4; ++i) {
        a[i] = *reinterpret_cast<const short8*>(&Asm[(wm + i * 16 + lr) * LDP + ks * 32 + lg * 8]);
        b[i] = *reinterpret_cast<const short8*>(&Bsm[(wn + i * 16 + lr) * LDP + ks * 32 + lg * 8]);
      }
#pragma unroll
      for (int i = 0; i < 4; ++i)
#pragma unroll
        for (int j = 0; j < 4; ++j)
          acc[i][j] = MFMA_BF16(a[i], b[j], acc[i][j], 0, 0, 0);
    }
  }

#pragma unroll
  for (int i = 0; i < 4; ++i) {
#pragma unroll
    for (int j = 0; j < 4; ++j) {
#pragma unroll
      for (int r = 0; r < 4; ++r) {
        const int grow = bm0 + wm + i * 16 + lg * 4 + r;
        const int gcol = bn0 + wn + j * 16 + lr;
        const size_t idx = (size_t)grow * NN + gcol;
        O[idx] = epilogue(acc[i][j][r], Y[idx]);
      }
    }
  }
}

// ---------------- naive fallback ----------------
__global__ void naive_fused(const float* __restrict__ X, const float* __restrict__ W,
                            const float* __restrict__ Y, float* __restrict__ O) {
  const int n0 = (blockIdx.x * 256 + threadIdx.x) * 4;
  const int m = blockIdx.y;
  f32x4 acc = {0.f, 0.f, 0.f, 0.f};
  const float* xr = &X[(size_t)m * KK];
  for (int k = 0; k < KK; ++k) {
    const float xv = xr[k];
    const f32x4 wv = *reinterpret_cast<const f32x4*>(&W[(size_t)k * NN + n0]);
    acc[0] += xv * wv[0];
    acc[1] += xv * wv[1];
    acc[2] += xv * wv[2];
    acc[3] += xv * wv[3];
  }
  const size_t idx = (size_t)m * NN + n0;
  O[idx + 0] = epilogue(acc[0], Y[idx + 0]);
  O[idx + 1] = epilogue(acc[1], Y[idx + 1]);
  O[idx + 2] = epilogue(acc[2], Y[idx + 2]);
  O[idx + 3] = epilogue(acc[3], Y[idx + 3]);
}

extern "C" void kernel_launch(void* const* d_in, const int* in_sizes, int n_in,
                              void* d_out, int out_size, void* d_ws, size_t ws_size,
                              hipStream_t stream) {
  const float* x = (const float*)d_in[0];
  const float* y = (const float*)d_in[1];
  const float* w = (const float*)d_in[2];
  float* out = (float*)d_out;

  const size_t xb_bytes = (size_t)MM * KK * sizeof(ushort_t);  // 67.1 MB
  const size_t wt_bytes = (size_t)NN * KK * sizeof(ushort_t);  // 33.5 MB

  if (ws_size >= xb_bytes + wt_bytes) {
    ushort_t* XB = (ushort_t*)d_ws;
    ushort_t* WT = (ushort_t*)((char*)d_ws + xb_bytes);
    hipLaunchKernelGGL((prep_kernel<1>), dim3(CVT_BLOCKS + WT_BLOCKS), dim3(256), 0, stream,
                       x, XB, w, WT);
    hipLaunchKernelGGL(gemm_bf16_d, dim3((MM / BM) * (NN / BN)), dim3(256), 0, stream,
                       XB, WT, y, out);
  } else if (ws_size >= wt_bytes) {
    ushort_t* WT = (ushort_t*)d_ws;
    hipLaunchKernelGGL((prep_kernel<0>), dim3(WT_BLOCKS), dim3(256), 0, stream,
                       x, nullptr, w, WT);
    hipLaunchKernelGGL(gemm_fused, dim3((MM / BM) * (NN / BN)), dim3(256), 0, stream,
                       x, WT, y, out);
  } else {
    hipLaunchKernelGGL(naive_fused, dim3(NN / 1024, MM), dim3(256), 0, stream, x, w, y, out);
  }
}